// Round 6
// baseline (260.733 us; speedup 1.0000x reference)
//
#include <hip/hip_runtime.h>
#include <hip/hip_bf16.h>

#define NN 100000      // nodes
#define NE 200000      // edges
#define NF 56          // atom feats
#define HD 256         // hidden
#define NG 2048        // graphs

#define SCAN_CH 512
#define NCH ((NN + SCAN_CH - 1) / SCAN_CH)   // 196 chunks
#define EB ((NE + 255) / 256)                // csr_fill edge blocks

#define AB 2048        // aggregate persistent blocks (4 waves each)
#define ZB 98          // deg-zero blocks in prep_params (25000 int4 / 256)
#define CVB ((NN + 255) / 256)               // x->bf16 convert blocks (391)
#define ENB ((NN + 127) / 128)               // 128-row GEMM blocks (782)

typedef __bf16 bf16x8 __attribute__((ext_vector_type(8)));
typedef __bf16 bf16x4 __attribute__((ext_vector_type(4)));
typedef float  floatx4 __attribute__((ext_vector_type(4)));

// ---- param prep (fully merged):
//   f <  NF              : delta-row GEMM -> dW0t (bf16, transposed, direct)
//   f == NF              : base row -> dW0t col 56 (rowsum trick); zero 57..63
//   f == NF+1            : layer-2 collapse params (w2lw, b2lw)
//   NF+2 .. NF+1+HD      : Wt row (layer-1 weight transpose-cast)
//   + ZB blocks          : zero deg[] (replaces hipMemsetAsync)
//   + CVB blocks         : x int32 [NN,56] -> xb bf16 [NN,64], col56 = 1.0
__global__ void prep_params(const float* __restrict__ emb, const float* __restrict__ Ws,
                            const float* __restrict__ bs, const float* __restrict__ lw,
                            __bf16* __restrict__ dW0t,
                            float* __restrict__ w2lw, float* __restrict__ b2lw,
                            __bf16* __restrict__ Wt, unsigned* __restrict__ deg,
                            const int* __restrict__ x, __bf16* __restrict__ xb) {
    __shared__ float row[HD];
    int c = threadIdx.x;
    int f = blockIdx.x;
    if (f >= NF + 2) {
        int g = f - (NF + 2);
        if (g < HD) {       // Wt[n=g][k=c] = Ws[1][c][g]
            Wt[(size_t)g * HD + c] = (__bf16)Ws[(size_t)HD * HD + (size_t)c * HD + g];
        } else if (g < HD + ZB) {   // zero deg as int4
            int idx = (g - HD) * HD + c;
            if (idx < NN / 4) ((int4*)deg)[idx] = make_int4(0, 0, 0, 0);
        } else {            // x -> bf16 pad-64 convert, col 56 = 1
            int r = (g - HD - ZB) * 256 + c;
            if (r < NN) {
                const int* xr = x + (size_t)r * NF;
                __bf16 o[64];
                #pragma unroll
                for (int j = 0; j < 14; ++j) {
                    int4 iv = *(const int4*)&xr[j * 4];
                    o[j * 4 + 0] = (__bf16)(float)iv.x;
                    o[j * 4 + 1] = (__bf16)(float)iv.y;
                    o[j * 4 + 2] = (__bf16)(float)iv.z;
                    o[j * 4 + 3] = (__bf16)(float)iv.w;
                }
                o[56] = (__bf16)1.0f;
                #pragma unroll
                for (int j = 57; j < 64; ++j) o[j] = (__bf16)0.0f;
                #pragma unroll
                for (int j = 0; j < 8; ++j)
                    *(bf16x8*)&xb[(size_t)r * 64 + j * 8] = *(const bf16x8*)&o[j * 8];
            }
        }
        return;
    }
    if (f == NF + 1) {   // layer-2 collapse params
        const float* W2 = Ws + (size_t)2 * HD * HD;
        float acc = 0.f;
        for (int k = 0; k < HD; ++k) acc += W2[(size_t)c * HD + k] * lw[k];
        w2lw[c] = acc;
        row[c] = bs[2 * HD + c] * lw[c];
        __syncthreads();
        for (int off = 128; off > 0; off >>= 1) {
            if (c < off) row[c] += row[c + off];
            __syncthreads();
        }
        if (c == 0) *b2lw = row[0];
        return;
    }
    if (f < NF) {
        row[c] = emb[(f * 2 + 1) * HD + c] - emb[(f * 2 + 0) * HD + c];
    } else {
        float s = 0.f;
        for (int ff = 0; ff < NF; ++ff) s += emb[(ff * 2) * HD + c];
        row[c] = s;
    }
    __syncthreads();
    float acc = 0.f;
    for (int k = 0; k < HD; ++k) acc += row[k] * Ws[k * HD + c];   // W0
    if (f < NF) {
        dW0t[c * 64 + f] = (__bf16)acc;          // transposed bf16, direct
    } else {
        dW0t[c * 64 + 56] = (__bf16)acc;         // base row via rowsum column
        #pragma unroll
        for (int k = 57; k < 64; ++k) dW0t[c * 64 + k] = (__bf16)0.f;
    }
}

// ---- degree ------------------------------------------------------------------
__global__ void deg_kernel(const int* __restrict__ dst, unsigned* __restrict__ deg, int E) {
    int e = blockIdx.x * blockDim.x + threadIdx.x;
    if (e < E) atomicAdd(&deg[dst[e]], 1u);
}

// merged: per-chunk degree sum (for scan) + dinv/selfn
__global__ void chunk_sum_dinv(const unsigned* __restrict__ deg, unsigned* __restrict__ csum,
                               float* __restrict__ dinv, float* __restrict__ selfn) {
    __shared__ unsigned s[SCAN_CH];
    int t = threadIdx.x;
    int base = blockIdx.x * SCAN_CH;
    unsigned v = (base + t < NN) ? deg[base + t] : 0u;
    s[t] = v;
    if (base + t < NN) {
        float d = (float)(v + 1u);   // +1 self loop
        dinv[base + t]  = rsqrtf(d);
        selfn[base + t] = 1.0f / d;
    }
    __syncthreads();
    for (int off = SCAN_CH / 2; off > 0; off >>= 1) {
        if (t < off) s[t] += s[t + off];
        __syncthreads();
    }
    if (t == 0) csum[blockIdx.x] = s[0];
}

// chunk_apply with INLINE scan of csum (each block re-scans 196 chunk sums)
__global__ void chunk_apply(const unsigned* __restrict__ deg, const unsigned* __restrict__ csum,
                            unsigned* __restrict__ row_start, unsigned* __restrict__ cursor) {
    __shared__ unsigned s[SCAN_CH];
    __shared__ unsigned cs[256];
    int t = threadIdx.x;
    if (t < 256) cs[t] = (t < NCH) ? csum[t] : 0u;
    __syncthreads();
    for (int off = 1; off < 256; off <<= 1) {
        unsigned add = (t < 256 && t >= off) ? cs[t - off] : 0u;
        __syncthreads();
        if (t < 256) cs[t] += add;
        __syncthreads();
    }
    unsigned chunk_base = (blockIdx.x == 0) ? 0u : cs[blockIdx.x - 1];

    int base = blockIdx.x * SCAN_CH;
    unsigned v = (base + t < NN) ? deg[base + t] : 0u;
    s[t] = v;
    __syncthreads();
    for (int off = 1; off < SCAN_CH; off <<= 1) {
        unsigned add = (t >= off) ? s[t - off] : 0u;
        __syncthreads();
        s[t] += add;
        __syncthreads();
    }
    if (base + t < NN) {
        unsigned rs = chunk_base + s[t] - v;   // exclusive scan value
        row_start[base + t] = rs;
        cursor[base + t] = rs;
    }
    if (blockIdx.x == 0 && t == 0) row_start[NN] = NE;
}

// csr_fill (inline norm) + graph_bounds merged into the tail blocks
__global__ void csr_fill_gb(const int* __restrict__ src, const int* __restrict__ dst,
                            const float* __restrict__ dinv, unsigned* __restrict__ cursor,
                            int* __restrict__ ecol, float* __restrict__ enorm,
                            const int* __restrict__ batch, unsigned* __restrict__ gstart) {
    int t = threadIdx.x;
    if (blockIdx.x < EB) {
        int e = blockIdx.x * 256 + t;
        if (e < NE) {
            int s = src[e], d = dst[e];
            unsigned pos = atomicAdd(&cursor[d], 1u);
            ecol[pos] = s;
            enorm[pos] = dinv[s] * dinv[d];
        }
    } else {
        int g = (blockIdx.x - EB) * 256 + t;
        if (g <= NG) {
            int lo = 0, hi = NN;
            while (lo < hi) {
                int mid = (lo + hi) >> 1;
                if (batch[mid] < g) lo = mid + 1; else hi = mid;
            }
            gstart[g] = (unsigned)lo;
        }
    }
}

// ---- fused layer-0: aggregate S.xb into LDS A-tile, then GEMM + BN stats ----
#define ELSTR 68
__global__ void __launch_bounds__(512) enc_fused(const __bf16* __restrict__ xb,
                                                 const __bf16* __restrict__ dW0t,
                                                 const float* __restrict__ b0,
                                                 const float* __restrict__ selfn,
                                                 const unsigned* __restrict__ row_start,
                                                 const int* __restrict__ ecol,
                                                 const float* __restrict__ enorm,
                                                 __bf16* __restrict__ C,
                                                 float* __restrict__ part) {
    __shared__ __bf16 sA[128 * ELSTR];   // 17408 B (aggregated A-tile)
    __shared__ __bf16 sB[256 * ELSTR];   // 34816 B
    __shared__ float psum[8][64];        // 2 KB
    __shared__ float psq[8][64];         // 2 KB
    int t = threadIdx.x;
    int m0 = blockIdx.x * 128;
    int lane = t & 63, w = t >> 6;
    int quad = lane >> 4, l16 = lane & 15;
    int mw = (w & 1) * 64, nw = (w >> 1) * 64;

    {   // B stage: 256 rows x 64 cols bf16
        int bn = t >> 1;
        int kh = (t & 1) * 32;
        #pragma unroll
        for (int j = 0; j < 4; ++j)
            *(bf16x8*)&sB[bn * ELSTR + kh + j * 8] =
                *(const bf16x8*)&dW0t[(size_t)bn * 64 + kh + j * 8];
    }
    {   // A stage = in-place aggregation: 4 threads per node, 16 cols each
        int r = t >> 2;
        int p = (t & 3) * 16;
        int n = m0 + r;
        float acc[16];
        #pragma unroll
        for (int i = 0; i < 16; ++i) acc[i] = 0.f;
        if (n < NN) {
            float sn = selfn[n];
            bf16x8 a0 = *(const bf16x8*)&xb[(size_t)n * 64 + p];
            bf16x8 a1 = *(const bf16x8*)&xb[(size_t)n * 64 + p + 8];
            #pragma unroll
            for (int i = 0; i < 8; ++i) {
                acc[i]     = (float)a0[i] * sn;
                acc[8 + i] = (float)a1[i] * sn;
            }
            unsigned e0 = row_start[n], e1 = row_start[n + 1];
            unsigned e = e0;
            for (; e + 2 <= e1; e += 2) {
                int s0 = ecol[e], s1 = ecol[e + 1];
                float n0v = enorm[e], n1v = enorm[e + 1];
                bf16x8 u00 = *(const bf16x8*)&xb[(size_t)s0 * 64 + p];
                bf16x8 u01 = *(const bf16x8*)&xb[(size_t)s0 * 64 + p + 8];
                bf16x8 u10 = *(const bf16x8*)&xb[(size_t)s1 * 64 + p];
                bf16x8 u11 = *(const bf16x8*)&xb[(size_t)s1 * 64 + p + 8];
                #pragma unroll
                for (int i = 0; i < 8; ++i) {
                    acc[i]     += (float)u00[i] * n0v + (float)u10[i] * n1v;
                    acc[8 + i] += (float)u01[i] * n0v + (float)u11[i] * n1v;
                }
            }
            if (e < e1) {
                int s0 = ecol[e];
                float n0v = enorm[e];
                bf16x8 u00 = *(const bf16x8*)&xb[(size_t)s0 * 64 + p];
                bf16x8 u01 = *(const bf16x8*)&xb[(size_t)s0 * 64 + p + 8];
                #pragma unroll
                for (int i = 0; i < 8; ++i) {
                    acc[i]     += (float)u00[i] * n0v;
                    acc[8 + i] += (float)u01[i] * n0v;
                }
            }
        }
        bf16x8 o0, o1;
        #pragma unroll
        for (int i = 0; i < 8; ++i) { o0[i] = (__bf16)acc[i]; o1[i] = (__bf16)acc[8 + i]; }
        *(bf16x8*)&sA[r * ELSTR + p]     = o0;
        *(bf16x8*)&sA[r * ELSTR + p + 8] = o1;
    }
    __syncthreads();

    floatx4 acc[4][4] = {};
    #pragma unroll
    for (int s = 0; s < 2; ++s) {
        bf16x8 af[4], bfr[4];
        #pragma unroll
        for (int i = 0; i < 4; ++i)
            af[i] = *(const bf16x8*)&sA[(mw + i * 16 + l16) * ELSTR + s * 32 + quad * 8];
        #pragma unroll
        for (int i = 0; i < 4; ++i)
            bfr[i] = *(const bf16x8*)&sB[(nw + i * 16 + l16) * ELSTR + s * 32 + quad * 8];
        #pragma unroll
        for (int mi = 0; mi < 4; ++mi)
            #pragma unroll
            for (int ni = 0; ni < 4; ++ni)
                acc[mi][ni] = __builtin_amdgcn_mfma_f32_16x16x32_bf16(
                    af[mi], bfr[ni], acc[mi][ni], 0, 0, 0);
    }

    float bw[4];
    #pragma unroll
    for (int ni = 0; ni < 4; ++ni) bw[ni] = b0[nw + ni * 16 + l16];
    float ls[4] = {0.f, 0.f, 0.f, 0.f};
    float lq[4] = {0.f, 0.f, 0.f, 0.f};
    #pragma unroll
    for (int mi = 0; mi < 4; ++mi) {
        #pragma unroll
        for (int r = 0; r < 4; ++r) {
            int row = m0 + mw + mi * 16 + quad * 4 + r;
            if (row < NN) {
                #pragma unroll
                for (int ni = 0; ni < 4; ++ni) {
                    float v = acc[mi][ni][r] + bw[ni];
                    C[(size_t)row * HD + nw + ni * 16 + l16] = (__bf16)v;
                    ls[ni] += v;
                    lq[ni] += v * v;
                }
            }
        }
    }
    // reduce across quads (rows) -> lanes 0..15 hold per-column partials
    #pragma unroll
    for (int ni = 0; ni < 4; ++ni) {
        ls[ni] += __shfl_xor(ls[ni], 16, 64);
        ls[ni] += __shfl_xor(ls[ni], 32, 64);
        lq[ni] += __shfl_xor(lq[ni], 16, 64);
        lq[ni] += __shfl_xor(lq[ni], 32, 64);
    }
    if (lane < 16) {
        #pragma unroll
        for (int ni = 0; ni < 4; ++ni) {
            psum[w][ni * 16 + l16] = ls[ni];
            psq[w][ni * 16 + l16]  = lq[ni];
        }
    }
    __syncthreads();
    if (!(w & 1) && lane < 16) {   // combine the two mw waves sharing nw
        #pragma unroll
        for (int ni = 0; ni < 4; ++ni) {
            int ci = ni * 16 + l16;
            part[(size_t)blockIdx.x * 512 + nw + ci]       = psum[w][ci] + psum[w + 1][ci];
            part[(size_t)blockIdx.x * 512 + 256 + nw + ci] = psq[w][ci]  + psq[w + 1][ci];
        }
    }
}

// ---- bf16 MFMA GEMM: 128x256 tile (full N), 512 thr / 8 waves (2m x 4n) -----
#define LSTR 36
__global__ void __launch_bounds__(512) gemm_mfma(const __bf16* __restrict__ A,
                                                 const __bf16* __restrict__ Wt,
                                                 __bf16* __restrict__ C, int M,
                                                 const float* __restrict__ ascale,
                                                 const float* __restrict__ ashift) {
    __shared__ __bf16 sA[128 * LSTR];   //  9216 B
    __shared__ __bf16 sB[256 * LSTR];   // 18432 B
    int t = threadIdx.x;                // 0..511
    int m0 = blockIdx.x * 128;
    int lane = t & 63, w = t >> 6;      // 8 waves
    int quad = lane >> 4, l16 = lane & 15;
    int mw = (w & 1) * 64;
    int nw = (w >> 1) * 64;             // 0,64,128,192

    int ar = t >> 2;          // A-stage row 0..127
    int ak = (t & 3) * 8;     // 16-B k-offset within 32-tile
    int bn = t >> 1;          // B-stage LDS row (n), 0..255
    int bk = (t & 1) * 16;    // k-offset (two bf16x8)

    auto ldA = [&](int k0, bf16x8& pa) {
        float4 s0 = *(const float4*)&ascale[k0 + ak];
        float4 s1 = *(const float4*)&ascale[k0 + ak + 4];
        float4 h0 = *(const float4*)&ashift[k0 + ak];
        float4 h1 = *(const float4*)&ashift[k0 + ak + 4];
        int row = m0 + ar;
        bf16x8 a = {};
        if (row < M) a = *(const bf16x8*)&A[(size_t)row * HD + k0 + ak];
        bf16x8 b;
        b[0] = (__bf16)fmaxf((float)a[0] * s0.x + h0.x, 0.f);
        b[1] = (__bf16)fmaxf((float)a[1] * s0.y + h0.y, 0.f);
        b[2] = (__bf16)fmaxf((float)a[2] * s0.z + h0.z, 0.f);
        b[3] = (__bf16)fmaxf((float)a[3] * s0.w + h0.w, 0.f);
        b[4] = (__bf16)fmaxf((float)a[4] * s1.x + h1.x, 0.f);
        b[5] = (__bf16)fmaxf((float)a[5] * s1.y + h1.y, 0.f);
        b[6] = (__bf16)fmaxf((float)a[6] * s1.z + h1.z, 0.f);
        b[7] = (__bf16)fmaxf((float)a[7] * s1.w + h1.w, 0.f);
        pa = b;
    };
    auto ldB = [&](int k0, bf16x8 pb[2]) {
        #pragma unroll
        for (int j = 0; j < 2; ++j)
            pb[j] = *(const bf16x8*)&Wt[(size_t)bn * HD + k0 + bk + j * 8];
    };

    bf16x8 pa, pb[2];
    ldA(0, pa);
    ldB(0, pb);

    floatx4 acc[4][4] = {};

    for (int k0 = 0; k0 < 256; k0 += 32) {
        *(bf16x8*)&sA[ar * LSTR + ak] = pa;
        *(bf16x8*)&sB[bn * LSTR + bk]     = pb[0];
        *(bf16x8*)&sB[bn * LSTR + bk + 8] = pb[1];
        __syncthreads();

        if (k0 + 32 < 256) {
            ldA(k0 + 32, pa);
            ldB(k0 + 32, pb);
        }

        bf16x8 af[4], bfr[4];
        #pragma unroll
        for (int i = 0; i < 4; ++i)
            af[i] = *(const bf16x8*)&sA[(mw + i * 16 + l16) * LSTR + quad * 8];
        #pragma unroll
        for (int i = 0; i < 4; ++i)
            bfr[i] = *(const bf16x8*)&sB[(nw + i * 16 + l16) * LSTR + quad * 8];
        #pragma unroll
        for (int mi = 0; mi < 4; ++mi)
            #pragma unroll
            for (int ni = 0; ni < 4; ++ni)
                acc[mi][ni] = __builtin_amdgcn_mfma_f32_16x16x32_bf16(
                    af[mi], bfr[ni], acc[mi][ni], 0, 0, 0);
        __syncthreads();
    }

    #pragma unroll
    for (int mi = 0; mi < 4; ++mi) {
        #pragma unroll
        for (int r = 0; r < 4; ++r) {
            int row = m0 + mw + mi * 16 + quad * 4 + r;
            if (row < M) {
                #pragma unroll
                for (int ni = 0; ni < 4; ++ni)
                    C[(size_t)row * HD + nw + ni * 16 + l16] = (__bf16)acc[mi][ni][r];
            }
        }
    }
}

// ---- CSR gather-aggregate + fused BN stats, NODE-PAIR edge pipeline ---------
// Each wave owns a consecutive node pair (n0,n0+1); their CSR ranges are
// contiguous, so ONE merged edge loop [r0,r2) keeps 4 gathers in flight
// regardless of per-node degree. Branchless routing via p/q norm split
// (wave-uniform compare -> cndmask), avoiding divergence & reg-indexing.
__global__ void __launch_bounds__(256) gcn_aggregate(const __bf16* __restrict__ hw,
                                                     const float* __restrict__ selfn,
                                                     const float* __restrict__ bias,
                                                     const unsigned* __restrict__ row_start,
                                                     const int* __restrict__ ecol,
                                                     const float* __restrict__ enorm,
                                                     __bf16* __restrict__ agg,
                                                     float* __restrict__ part) {
    int t = threadIdx.x;
    int l = t & 63, w = t >> 6;
    int c4 = l * 4;
    float4 bv = *(const float4*)&bias[c4];
    float4 lsum = make_float4(0.f, 0.f, 0.f, 0.f);
    float4 lssq = make_float4(0.f, 0.f, 0.f, 0.f);

    for (int n0 = blockIdx.x * 8 + w * 2; n0 < NN; n0 += AB * 8) {
        int n1 = n0 + 1;   // NN even, n0 even -> n1 < NN always
        float sn0 = selfn[n0], sn1 = selfn[n1];
        bf16x4 h0 = *(const bf16x4*)&hw[(size_t)n0 * HD + c4];
        bf16x4 h1 = *(const bf16x4*)&hw[(size_t)n1 * HD + c4];
        float4 a0, a1;
        a0.x = (float)h0[0] * sn0 + bv.x;
        a0.y = (float)h0[1] * sn0 + bv.y;
        a0.z = (float)h0[2] * sn0 + bv.z;
        a0.w = (float)h0[3] * sn0 + bv.w;
        a1.x = (float)h1[0] * sn1 + bv.x;
        a1.y = (float)h1[1] * sn1 + bv.y;
        a1.z = (float)h1[2] * sn1 + bv.z;
        a1.w = (float)h1[3] * sn1 + bv.w;
        unsigned r0 = row_start[n0];
        unsigned r1 = row_start[n1];
        unsigned r2 = row_start[n1 + 1];
        unsigned e = r0;
        for (; e + 4 <= r2; e += 4) {
            int sv0 = ecol[e], sv1 = ecol[e + 1], sv2 = ecol[e + 2], sv3 = ecol[e + 3];
            float nm0 = enorm[e], nm1 = enorm[e + 1], nm2 = enorm[e + 2], nm3 = enorm[e + 3];
            bf16x4 u0 = *(const bf16x4*)&hw[(size_t)sv0 * HD + c4];
            bf16x4 u1 = *(const bf16x4*)&hw[(size_t)sv1 * HD + c4];
            bf16x4 u2 = *(const bf16x4*)&hw[(size_t)sv2 * HD + c4];
            bf16x4 u3 = *(const bf16x4*)&hw[(size_t)sv3 * HD + c4];
            float p0 = (e + 0 < r1) ? nm0 : 0.f, q0 = nm0 - p0;
            float p1 = (e + 1 < r1) ? nm1 : 0.f, q1 = nm1 - p1;
            float p2 = (e + 2 < r1) ? nm2 : 0.f, q2 = nm2 - p2;
            float p3 = (e + 3 < r1) ? nm3 : 0.f, q3 = nm3 - p3;
            a0.x += (float)u0[0] * p0 + (float)u1[0] * p1 + (float)u2[0] * p2 + (float)u3[0] * p3;
            a0.y += (float)u0[1] * p0 + (float)u1[1] * p1 + (float)u2[1] * p2 + (float)u3[1] * p3;
            a0.z += (float)u0[2] * p0 + (float)u1[2] * p1 + (float)u2[2] * p2 + (float)u3[2] * p3;
            a0.w += (float)u0[3] * p0 + (float)u1[3] * p1 + (float)u2[3] * p2 + (float)u3[3] * p3;
            a1.x += (float)u0[0] * q0 + (float)u1[0] * q1 + (float)u2[0] * q2 + (float)u3[0] * q3;
            a1.y += (float)u0[1] * q0 + (float)u1[1] * q1 + (float)u2[1] * q2 + (float)u3[1] * q3;
            a1.z += (float)u0[2] * q0 + (float)u1[2] * q1 + (float)u2[2] * q2 + (float)u3[2] * q3;
            a1.w += (float)u0[3] * q0 + (float)u1[3] * q1 + (float)u2[3] * q2 + (float)u3[3] * q3;
        }
        for (; e + 2 <= r2; e += 2) {
            int sv0 = ecol[e], sv1 = ecol[e + 1];
            float nm0 = enorm[e], nm1 = enorm[e + 1];
            bf16x4 u0 = *(const bf16x4*)&hw[(size_t)sv0 * HD + c4];
            bf16x4 u1 = *(const bf16x4*)&hw[(size_t)sv1 * HD + c4];
            float p0 = (e + 0 < r1) ? nm0 : 0.f, q0 = nm0 - p0;
            float p1 = (e + 1 < r1) ? nm1 : 0.f, q1 = nm1 - p1;
            a0.x += (float)u0[0] * p0 + (float)u1[0] * p1;
            a0.y += (float)u0[1] * p0 + (float)u1[1] * p1;
            a0.z += (float)u0[2] * p0 + (float)u1[2] * p1;
            a0.w += (float)u0[3] * p0 + (float)u1[3] * p1;
            a1.x += (float)u0[0] * q0 + (float)u1[0] * q1;
            a1.y += (float)u0[1] * q0 + (float)u1[1] * q1;
            a1.z += (float)u0[2] * q0 + (float)u1[2] * q1;
            a1.w += (float)u0[3] * q0 + (float)u1[3] * q1;
        }
        if (e < r2) {
            int sv = ecol[e];
            float nm = enorm[e];
            bf16x4 u = *(const bf16x4*)&hw[(size_t)sv * HD + c4];
            float p = (e < r1) ? nm : 0.f, q = nm - p;
            a0.x += (float)u[0] * p;
            a0.y += (float)u[1] * p;
            a0.z += (float)u[2] * p;
            a0.w += (float)u[3] * p;
            a1.x += (float)u[0] * q;
            a1.y += (float)u[1] * q;
            a1.z += (float)u[2] * q;
            a1.w += (float)u[3] * q;
        }
        bf16x4 o0, o1;
        o0[0] = (__bf16)a0.x; o0[1] = (__bf16)a0.y;
        o0[2] = (__bf16)a0.z; o0[3] = (__bf16)a0.w;
        o1[0] = (__bf16)a1.x; o1[1] = (__bf16)a1.y;
        o1[2] = (__bf16)a1.z; o1[3] = (__bf16)a1.w;
        *(bf16x4*)&agg[(size_t)n0 * HD + c4] = o0;
        *(bf16x4*)&agg[(size_t)n1 * HD + c4] = o1;

        lsum.x += a0.x + a1.x; lsum.y += a0.y + a1.y;
        lsum.z += a0.z + a1.z; lsum.w += a0.w + a1.w;
        lssq.x += a0.x * a0.x + a1.x * a1.x;
        lssq.y += a0.y * a0.y + a1.y * a1.y;
        lssq.z += a0.z * a0.z + a1.z * a1.z;
        lssq.w += a0.w * a0.w + a1.w * a1.w;
    }

    __shared__ float4 ssum[4][64];
    __shared__ float4 sss[4][64];
    ssum[w][l] = lsum;
    sss[w][l]  = lssq;
    __syncthreads();
    if (w == 0) {
        float4 a0 = ssum[0][l], a1 = ssum[1][l], a2 = ssum[2][l], a3 = ssum[3][l];
        float4 q0 = sss[0][l],  q1 = sss[1][l],  q2 = sss[2][l],  q3 = sss[3][l];
        float4 sm, sq;
        sm.x = a0.x + a1.x + a2.x + a3.x;
        sm.y = a0.y + a1.y + a2.y + a3.y;
        sm.z = a0.z + a1.z + a2.z + a3.z;
        sm.w = a0.w + a1.w + a2.w + a3.w;
        sq.x = q0.x + q1.x + q2.x + q3.x;
        sq.y = q0.y + q1.y + q2.y + q3.y;
        sq.z = q0.z + q1.z + q2.z + q3.z;
        sq.w = q0.w + q1.w + q2.w + q3.w;
        *(float4*)&part[(size_t)blockIdx.x * 512 + c4]       = sm;   // contiguous 2 KB/block
        *(float4*)&part[(size_t)blockIdx.x * 512 + 256 + c4] = sq;
    }
}

// Stage 2: one block per column c; reduce nb per-block partials, emit scale/shift.
__global__ void __launch_bounds__(256) bn_scale(const float* __restrict__ part, int nb,
                                                const float* __restrict__ gamma,
                                                const float* __restrict__ beta,
                                                float* __restrict__ scale,
                                                float* __restrict__ shift) {
    __shared__ float rs[256], rq[256];
    int t = threadIdx.x;
    int c = blockIdx.x;
    float s = 0.f, q = 0.f;
    for (int j = t; j < nb; j += 256) {
        s += part[(size_t)j * 512 + c];
        q += part[(size_t)j * 512 + 256 + c];
    }
    rs[t] = s; rq[t] = q;
    __syncthreads();
    for (int off = 128; off > 0; off >>= 1) {
        if (t < off) { rs[t] += rs[t + off]; rq[t] += rq[t + off]; }
        __syncthreads();
    }
    if (t == 0) {
        const float inv_n = 1.0f / (float)NN;
        float mu  = rs[0] * inv_n;
        float var = rq[0] * inv_n - mu * mu;
        float rstd = rsqrtf(var + 1e-5f);
        float sc = gamma[c] * rstd;
        scale[c] = sc;
        shift[c] = beta[c] - mu * sc;
    }
}

// ---- layer-2 collapse: z[n] = relu_bn(buf0[n]) . w2lw  (one wave per node) --
__global__ void __launch_bounds__(256) bn_dot(const __bf16* __restrict__ h,
                                              const float* __restrict__ scale,
                                              const float* __restrict__ shift,
                                              const float* __restrict__ w2lw,
                                              float* __restrict__ z) {
    int tid = blockIdx.x * 256 + threadIdx.x;
    int n = tid >> 6;
    if (n >= NN) return;
    int l = tid & 63;
    int c4 = l * 4;
    bf16x4 a = *(const bf16x4*)&h[(size_t)n * HD + c4];
    float4 sc = *(const float4*)&scale[c4];
    float4 sh = *(const float4*)&shift[c4];
    float4 wv = *(const float4*)&w2lw[c4];
    float d = fmaxf((float)a[0] * sc.x + sh.x, 0.f) * wv.x
            + fmaxf((float)a[1] * sc.y + sh.y, 0.f) * wv.y
            + fmaxf((float)a[2] * sc.z + sh.z, 0.f) * wv.z
            + fmaxf((float)a[3] * sc.w + sh.w, 0.f) * wv.w;
    #pragma unroll
    for (int off = 32; off > 0; off >>= 1) d += __shfl_down(d, off, 64);
    if (l == 0) z[n] = d;
}

// ---- fused final: per-graph wave; lanes stride nodes; scalar edge loop ------
__global__ void __launch_bounds__(256) pool_fused(const float* __restrict__ z,
                                                  const float* __restrict__ selfn,
                                                  const float* __restrict__ b2lw,
                                                  const unsigned* __restrict__ row_start,
                                                  const int* __restrict__ ecol,
                                                  const float* __restrict__ enorm,
                                                  const unsigned* __restrict__ gstart,
                                                  const float* __restrict__ lb,
                                                  float* __restrict__ out) {
    int tid = blockIdx.x * 256 + threadIdx.x;
    int g = tid >> 6;
    if (g >= NG) return;
    int l = tid & 63;
    unsigned s0 = gstart[g], s1 = gstart[g + 1];
    float bb = *b2lw;
    float s = 0.f;
    for (unsigned i = s0 + l; i < s1; i += 64) {
        float d = selfn[i] * z[i] + bb;
        unsigned e0 = row_start[i], e1 = row_start[i + 1];
        for (unsigned e = e0; e < e1; ++e)
            d += enorm[e] * z[ecol[e]];
        s += d;
    }
    #pragma unroll
    for (int off = 32; off > 0; off >>= 1) s += __shfl_down(s, off, 64);
    if (l == 0) out[g] = s / fmaxf((float)(s1 - s0), 1.0f) + lb[0];
}

// ---- driver -----------------------------------------------------------------
extern "C" void kernel_launch(void* const* d_in, const int* in_sizes, int n_in,
                              void* d_out, int out_size, void* d_ws, size_t ws_size,
                              hipStream_t stream) {
    const int*   x     = (const int*)d_in[0];
    const int*   ei    = (const int*)d_in[1];
    const int*   batch = (const int*)d_in[2];
    const float* emb   = (const float*)d_in[3];
    const float* Ws    = (const float*)d_in[4];
    const float* bs    = (const float*)d_in[5];
    const float* gam   = (const float*)d_in[6];
    const float* bet   = (const float*)d_in[7];
    const float* lw    = (const float*)d_in[8];
    const float* lb    = (const float*)d_in[9];
    float* out = (float*)d_out;

    const int* src = ei;
    const int* dst = ei + NE;

    // workspace carve-up (256-B aligned)
    char* p = (char*)d_ws;
    size_t off = 0;
    auto carve = [&](size_t bytes) { void* r = p + off; off = (off + bytes + 255) & ~(size_t)255; return r; };
    __bf16*   buf0   = (__bf16*)carve((size_t)NN * HD * 2);   // conv0 / conv1 (bf16)
    __bf16*   buf1   = (__bf16*)carve((size_t)NN * HD * 2);   // hw1 (bf16)
    __bf16*   xb     = (__bf16*)carve((size_t)NN * 64 * 2);   // x as bf16, pad 64
    __bf16*   dW0t   = (__bf16*)carve(HD * 64 * 2);
    __bf16*   Wt     = (__bf16*)carve((size_t)HD * HD * 2);   // layer-1 only
    float*    w2lw   = (float*)carve(HD * 4);
    float*    b2lw   = (float*)carve(256);
    unsigned* deg    = (unsigned*)carve(NN * 4);
    float*    dinv   = (float*)carve(NN * 4);
    float*    selfn  = (float*)carve(NN * 4);
    unsigned* csum   = (unsigned*)carve(256 * 4);
    unsigned* row_s  = (unsigned*)carve((NN + 1) * 4);
    unsigned* cursor = (unsigned*)carve(NN * 4);
    int*      ecol   = (int*)carve(NE * 4);
    float*    enorm  = (float*)carve(NE * 4);
    float*    part   = (float*)carve((size_t)AB * 512 * 4);   // 4 MB, [blk][512]
    float*    scale  = (float*)carve(HD * 4);
    float*    shift  = (float*)carve(HD * 4);
    unsigned* gstart = (unsigned*)carve((NG + 1) * 4);
    float*    zbuf   = (float*)carve(NN * 4);
    (void)ws_size; (void)n_in; (void)in_sizes; (void)out_size;

    // params + weight transposes + deg zeroing + x->bf16, all in one dispatch
    prep_params<<<NF + 2 + HD + ZB + CVB, HD, 0, stream>>>(
        emb, Ws, bs, lw, dW0t, w2lw, b2lw, Wt, deg, x, xb);

    // degrees, CSR build with inline norm + graph bounds in tail blocks
    deg_kernel<<<(NE + 255) / 256, 256, 0, stream>>>(dst, deg, NE);
    chunk_sum_dinv<<<NCH, SCAN_CH, 0, stream>>>(deg, csum, dinv, selfn);
    chunk_apply<<<NCH, SCAN_CH, 0, stream>>>(deg, csum, row_s, cursor);
    csr_fill_gb<<<EB + (NG + 256) / 256, 256, 0, stream>>>(
        src, dst, dinv, cursor, ecol, enorm, batch, gstart);

    // layer 0: aggregate-into-LDS + encoder GEMM + BN stats, one kernel
    enc_fused<<<ENB, 512, 0, stream>>>(
        xb, dW0t, bs, selfn, row_s, ecol, enorm, buf0, part);
    bn_scale<<<HD, 256, 0, stream>>>(part, ENB, gam, bet, scale, shift);

    // layer 1: MFMA GEMM (bn+relu fused on A-load) -> buf1, aggregate+stats -> buf0
    gemm_mfma<<<ENB, 512, 0, stream>>>(buf0, Wt, buf1, NN, scale, shift);
    gcn_aggregate<<<AB, 256, 0, stream>>>(
        buf1, selfn, bs + HD, row_s, ecol, enorm, buf0, part);
    bn_scale<<<HD, 256, 0, stream>>>(part, AB, gam + HD, bet + HD, scale, shift);

    // layer 2 (collapsed): z = relu_bn(buf0)@(W2 lw); fused agg+pool
    bn_dot<<<(NN * 64 + 255) / 256, 256, 0, stream>>>(buf0, scale, shift, w2lw, zbuf);
    pool_fused<<<(NG * 64 + 255) / 256, 256, 0, stream>>>(
        zbuf, selfn, b2lw, row_s, ecol, enorm, gstart, lb, out);
}

// Round 7
// 248.489 us; speedup vs baseline: 1.0493x; 1.0493x over previous
//
#include <hip/hip_runtime.h>
#include <hip/hip_bf16.h>

#define NN 100000      // nodes
#define NE 200000      // edges
#define NF 56          // atom feats
#define HD 256         // hidden
#define NG 2048        // graphs

#define SCAN_CH 512
#define NCH ((NN + SCAN_CH - 1) / SCAN_CH)   // 196 chunks
#define EB ((NE + 255) / 256)                // csr_fill edge blocks

#define ZB 98          // deg-zero blocks in prep_params (25000 int4 / 256)
#define CVB ((NN + 255) / 256)               // x->bf16 convert blocks (391)
#define ENB ((NN + 127) / 128)               // 128-row encoder blocks (782)
#define GNB ((NN + 63) / 64)                 // 64-row fused layer-1 blocks (1563)

typedef __bf16 bf16x8 __attribute__((ext_vector_type(8)));
typedef __bf16 bf16x4 __attribute__((ext_vector_type(4)));
typedef float  floatx4 __attribute__((ext_vector_type(4)));

// ---- param prep (fully merged):
//   f <  NF              : delta-row GEMM -> dW0t (bf16, transposed, direct)
//   f == NF              : base row -> dW0t col 56 (rowsum trick); zero 57..63
//   f == NF+1            : layer-2 collapse params (w2lw, b2lw)
//   NF+2 .. NF+1+HD      : Wt row (layer-1 weight transpose-cast)
//   + ZB blocks          : zero deg[] (replaces hipMemsetAsync)
//   + CVB blocks         : x int32 [NN,56] -> xb bf16 [NN,64], col56 = 1.0
__global__ void prep_params(const float* __restrict__ emb, const float* __restrict__ Ws,
                            const float* __restrict__ bs, const float* __restrict__ lw,
                            __bf16* __restrict__ dW0t,
                            float* __restrict__ w2lw, float* __restrict__ b2lw,
                            __bf16* __restrict__ Wt, unsigned* __restrict__ deg,
                            const int* __restrict__ x, __bf16* __restrict__ xb) {
    __shared__ float row[HD];
    int c = threadIdx.x;
    int f = blockIdx.x;
    if (f >= NF + 2) {
        int g = f - (NF + 2);
        if (g < HD) {       // Wt[n=g][k=c] = Ws[1][c][g]
            Wt[(size_t)g * HD + c] = (__bf16)Ws[(size_t)HD * HD + (size_t)c * HD + g];
        } else if (g < HD + ZB) {   // zero deg as int4
            int idx = (g - HD) * HD + c;
            if (idx < NN / 4) ((int4*)deg)[idx] = make_int4(0, 0, 0, 0);
        } else {            // x -> bf16 pad-64 convert, col 56 = 1
            int r = (g - HD - ZB) * 256 + c;
            if (r < NN) {
                const int* xr = x + (size_t)r * NF;
                __bf16 o[64];
                #pragma unroll
                for (int j = 0; j < 14; ++j) {
                    int4 iv = *(const int4*)&xr[j * 4];
                    o[j * 4 + 0] = (__bf16)(float)iv.x;
                    o[j * 4 + 1] = (__bf16)(float)iv.y;
                    o[j * 4 + 2] = (__bf16)(float)iv.z;
                    o[j * 4 + 3] = (__bf16)(float)iv.w;
                }
                o[56] = (__bf16)1.0f;
                #pragma unroll
                for (int j = 57; j < 64; ++j) o[j] = (__bf16)0.0f;
                #pragma unroll
                for (int j = 0; j < 8; ++j)
                    *(bf16x8*)&xb[(size_t)r * 64 + j * 8] = *(const bf16x8*)&o[j * 8];
            }
        }
        return;
    }
    if (f == NF + 1) {   // layer-2 collapse params
        const float* W2 = Ws + (size_t)2 * HD * HD;
        float acc = 0.f;
        for (int k = 0; k < HD; ++k) acc += W2[(size_t)c * HD + k] * lw[k];
        w2lw[c] = acc;
        row[c] = bs[2 * HD + c] * lw[c];
        __syncthreads();
        for (int off = 128; off > 0; off >>= 1) {
            if (c < off) row[c] += row[c + off];
            __syncthreads();
        }
        if (c == 0) *b2lw = row[0];
        return;
    }
    if (f < NF) {
        row[c] = emb[(f * 2 + 1) * HD + c] - emb[(f * 2 + 0) * HD + c];
    } else {
        float s = 0.f;
        for (int ff = 0; ff < NF; ++ff) s += emb[(ff * 2) * HD + c];
        row[c] = s;
    }
    __syncthreads();
    float acc = 0.f;
    for (int k = 0; k < HD; ++k) acc += row[k] * Ws[k * HD + c];   // W0
    if (f < NF) {
        dW0t[c * 64 + f] = (__bf16)acc;          // transposed bf16, direct
    } else {
        dW0t[c * 64 + 56] = (__bf16)acc;         // base row via rowsum column
        #pragma unroll
        for (int k = 57; k < 64; ++k) dW0t[c * 64 + k] = (__bf16)0.f;
    }
}

// ---- degree ------------------------------------------------------------------
__global__ void deg_kernel(const int* __restrict__ dst, unsigned* __restrict__ deg, int E) {
    int e = blockIdx.x * blockDim.x + threadIdx.x;
    if (e < E) atomicAdd(&deg[dst[e]], 1u);
}

// merged: per-chunk degree sum (for scan) + dinv/selfn
__global__ void chunk_sum_dinv(const unsigned* __restrict__ deg, unsigned* __restrict__ csum,
                               float* __restrict__ dinv, float* __restrict__ selfn) {
    __shared__ unsigned s[SCAN_CH];
    int t = threadIdx.x;
    int base = blockIdx.x * SCAN_CH;
    unsigned v = (base + t < NN) ? deg[base + t] : 0u;
    s[t] = v;
    if (base + t < NN) {
        float d = (float)(v + 1u);   // +1 self loop
        dinv[base + t]  = rsqrtf(d);
        selfn[base + t] = 1.0f / d;
    }
    __syncthreads();
    for (int off = SCAN_CH / 2; off > 0; off >>= 1) {
        if (t < off) s[t] += s[t + off];
        __syncthreads();
    }
    if (t == 0) csum[blockIdx.x] = s[0];
}

// chunk_apply with INLINE scan of csum (each block re-scans 196 chunk sums)
__global__ void chunk_apply(const unsigned* __restrict__ deg, const unsigned* __restrict__ csum,
                            unsigned* __restrict__ row_start, unsigned* __restrict__ cursor) {
    __shared__ unsigned s[SCAN_CH];
    __shared__ unsigned cs[256];
    int t = threadIdx.x;
    if (t < 256) cs[t] = (t < NCH) ? csum[t] : 0u;
    __syncthreads();
    for (int off = 1; off < 256; off <<= 1) {
        unsigned add = (t < 256 && t >= off) ? cs[t - off] : 0u;
        __syncthreads();
        if (t < 256) cs[t] += add;
        __syncthreads();
    }
    unsigned chunk_base = (blockIdx.x == 0) ? 0u : cs[blockIdx.x - 1];

    int base = blockIdx.x * SCAN_CH;
    unsigned v = (base + t < NN) ? deg[base + t] : 0u;
    s[t] = v;
    __syncthreads();
    for (int off = 1; off < SCAN_CH; off <<= 1) {
        unsigned add = (t >= off) ? s[t - off] : 0u;
        __syncthreads();
        s[t] += add;
        __syncthreads();
    }
    if (base + t < NN) {
        unsigned rs = chunk_base + s[t] - v;   // exclusive scan value
        row_start[base + t] = rs;
        cursor[base + t] = rs;
    }
    if (blockIdx.x == 0 && t == 0) row_start[NN] = NE;
}

// csr_fill (inline norm) + graph_bounds merged into the tail blocks
__global__ void csr_fill_gb(const int* __restrict__ src, const int* __restrict__ dst,
                            const float* __restrict__ dinv, unsigned* __restrict__ cursor,
                            int* __restrict__ ecol, float* __restrict__ enorm,
                            const int* __restrict__ batch, unsigned* __restrict__ gstart) {
    int t = threadIdx.x;
    if (blockIdx.x < EB) {
        int e = blockIdx.x * 256 + t;
        if (e < NE) {
            int s = src[e], d = dst[e];
            unsigned pos = atomicAdd(&cursor[d], 1u);
            ecol[pos] = s;
            enorm[pos] = dinv[s] * dinv[d];
        }
    } else {
        int g = (blockIdx.x - EB) * 256 + t;
        if (g <= NG) {
            int lo = 0, hi = NN;
            while (lo < hi) {
                int mid = (lo + hi) >> 1;
                if (batch[mid] < g) lo = mid + 1; else hi = mid;
            }
            gstart[g] = (unsigned)lo;
        }
    }
}

// ---- fused layer-0: aggregate S.xb into LDS A-tile, then GEMM + BN stats ----
#define ELSTR 68
__global__ void __launch_bounds__(512) enc_fused(const __bf16* __restrict__ xb,
                                                 const __bf16* __restrict__ dW0t,
                                                 const float* __restrict__ b0,
                                                 const float* __restrict__ selfn,
                                                 const unsigned* __restrict__ row_start,
                                                 const int* __restrict__ ecol,
                                                 const float* __restrict__ enorm,
                                                 __bf16* __restrict__ C,
                                                 float* __restrict__ part) {
    __shared__ __bf16 sA[128 * ELSTR];   // 17408 B (aggregated A-tile)
    __shared__ __bf16 sB[256 * ELSTR];   // 34816 B
    __shared__ float psum[8][64];        // 2 KB
    __shared__ float psq[8][64];         // 2 KB
    int t = threadIdx.x;
    int m0 = blockIdx.x * 128;
    int lane = t & 63, w = t >> 6;
    int quad = lane >> 4, l16 = lane & 15;
    int mw = (w & 1) * 64, nw = (w >> 1) * 64;

    {   // B stage: 256 rows x 64 cols bf16
        int bn = t >> 1;
        int kh = (t & 1) * 32;
        #pragma unroll
        for (int j = 0; j < 4; ++j)
            *(bf16x8*)&sB[bn * ELSTR + kh + j * 8] =
                *(const bf16x8*)&dW0t[(size_t)bn * 64 + kh + j * 8];
    }
    {   // A stage = in-place aggregation: 4 threads per node, 16 cols each
        int r = t >> 2;
        int p = (t & 3) * 16;
        int n = m0 + r;
        float acc[16];
        #pragma unroll
        for (int i = 0; i < 16; ++i) acc[i] = 0.f;
        if (n < NN) {
            float sn = selfn[n];
            bf16x8 a0 = *(const bf16x8*)&xb[(size_t)n * 64 + p];
            bf16x8 a1 = *(const bf16x8*)&xb[(size_t)n * 64 + p + 8];
            #pragma unroll
            for (int i = 0; i < 8; ++i) {
                acc[i]     = (float)a0[i] * sn;
                acc[8 + i] = (float)a1[i] * sn;
            }
            unsigned e0 = row_start[n], e1 = row_start[n + 1];
            unsigned e = e0;
            for (; e + 2 <= e1; e += 2) {
                int s0 = ecol[e], s1 = ecol[e + 1];
                float n0v = enorm[e], n1v = enorm[e + 1];
                bf16x8 u00 = *(const bf16x8*)&xb[(size_t)s0 * 64 + p];
                bf16x8 u01 = *(const bf16x8*)&xb[(size_t)s0 * 64 + p + 8];
                bf16x8 u10 = *(const bf16x8*)&xb[(size_t)s1 * 64 + p];
                bf16x8 u11 = *(const bf16x8*)&xb[(size_t)s1 * 64 + p + 8];
                #pragma unroll
                for (int i = 0; i < 8; ++i) {
                    acc[i]     += (float)u00[i] * n0v + (float)u10[i] * n1v;
                    acc[8 + i] += (float)u01[i] * n0v + (float)u11[i] * n1v;
                }
            }
            if (e < e1) {
                int s0 = ecol[e];
                float n0v = enorm[e];
                bf16x8 u00 = *(const bf16x8*)&xb[(size_t)s0 * 64 + p];
                bf16x8 u01 = *(const bf16x8*)&xb[(size_t)s0 * 64 + p + 8];
                #pragma unroll
                for (int i = 0; i < 8; ++i) {
                    acc[i]     += (float)u00[i] * n0v;
                    acc[8 + i] += (float)u01[i] * n0v;
                }
            }
        }
        bf16x8 o0, o1;
        #pragma unroll
        for (int i = 0; i < 8; ++i) { o0[i] = (__bf16)acc[i]; o1[i] = (__bf16)acc[8 + i]; }
        *(bf16x8*)&sA[r * ELSTR + p]     = o0;
        *(bf16x8*)&sA[r * ELSTR + p + 8] = o1;
    }
    __syncthreads();

    floatx4 acc[4][4] = {};
    #pragma unroll
    for (int s = 0; s < 2; ++s) {
        bf16x8 af[4], bfr[4];
        #pragma unroll
        for (int i = 0; i < 4; ++i)
            af[i] = *(const bf16x8*)&sA[(mw + i * 16 + l16) * ELSTR + s * 32 + quad * 8];
        #pragma unroll
        for (int i = 0; i < 4; ++i)
            bfr[i] = *(const bf16x8*)&sB[(nw + i * 16 + l16) * ELSTR + s * 32 + quad * 8];
        #pragma unroll
        for (int mi = 0; mi < 4; ++mi)
            #pragma unroll
            for (int ni = 0; ni < 4; ++ni)
                acc[mi][ni] = __builtin_amdgcn_mfma_f32_16x16x32_bf16(
                    af[mi], bfr[ni], acc[mi][ni], 0, 0, 0);
    }

    float bw[4];
    #pragma unroll
    for (int ni = 0; ni < 4; ++ni) bw[ni] = b0[nw + ni * 16 + l16];
    float ls[4] = {0.f, 0.f, 0.f, 0.f};
    float lq[4] = {0.f, 0.f, 0.f, 0.f};
    #pragma unroll
    for (int mi = 0; mi < 4; ++mi) {
        #pragma unroll
        for (int r = 0; r < 4; ++r) {
            int row = m0 + mw + mi * 16 + quad * 4 + r;
            if (row < NN) {
                #pragma unroll
                for (int ni = 0; ni < 4; ++ni) {
                    float v = acc[mi][ni][r] + bw[ni];
                    C[(size_t)row * HD + nw + ni * 16 + l16] = (__bf16)v;
                    ls[ni] += v;
                    lq[ni] += v * v;
                }
            }
        }
    }
    // reduce across quads (rows) -> lanes 0..15 hold per-column partials
    #pragma unroll
    for (int ni = 0; ni < 4; ++ni) {
        ls[ni] += __shfl_xor(ls[ni], 16, 64);
        ls[ni] += __shfl_xor(ls[ni], 32, 64);
        lq[ni] += __shfl_xor(lq[ni], 16, 64);
        lq[ni] += __shfl_xor(lq[ni], 32, 64);
    }
    if (lane < 16) {
        #pragma unroll
        for (int ni = 0; ni < 4; ++ni) {
            psum[w][ni * 16 + l16] = ls[ni];
            psq[w][ni * 16 + l16]  = lq[ni];
        }
    }
    __syncthreads();
    if (!(w & 1) && lane < 16) {   // combine the two mw waves sharing nw
        #pragma unroll
        for (int ni = 0; ni < 4; ++ni) {
            int ci = ni * 16 + l16;
            part[(size_t)blockIdx.x * 512 + nw + ci]       = psum[w][ci] + psum[w + 1][ci];
            part[(size_t)blockIdx.x * 512 + 256 + nw + ci] = psq[w][ci]  + psq[w + 1][ci];
        }
    }
}

// ---- fused layer-1: conv1 = (S . relu_bn(conv0)) @ W1 + b1, + BN stats ------
// M-tile 64, 512 thr / 8 waves. Phase A: wave-per-node (8 nodes/wave) aggregates
// S.relu_bn(conv0) into a granule-XOR-swizzled LDS A-tile (linear 512B rows are
// a 16-way bank conflict on ds_read_b128; swz = granule ^ (row&7) fixes it).
// Phase B: K=256 GEMM, B streamed in 32-K chunks with register prefetch.
// Wave w owns output cols [w*32, w*32+32) -> per-column BN stats need no LDS.
__global__ void __launch_bounds__(512) gcn_fused(const __bf16* __restrict__ h0,
                                                 const float* __restrict__ scale,
                                                 const float* __restrict__ shift,
                                                 const __bf16* __restrict__ Wt,
                                                 const float* __restrict__ b1,
                                                 const float* __restrict__ selfn,
                                                 const unsigned* __restrict__ row_start,
                                                 const int* __restrict__ ecol,
                                                 const float* __restrict__ enorm,
                                                 __bf16* __restrict__ C,
                                                 float* __restrict__ part) {
    __shared__ __bf16 sA[64 * 256];    // 32 KB, swizzled
    __shared__ __bf16 sB[256 * 36];    // 18 KB (32-K chunk, LSTR pad)
    int t = threadIdx.x;
    int m0 = blockIdx.x * 64;
    int lane = t & 63, w = t >> 6;
    int quad = lane >> 4, l16 = lane & 15;

    // B chunk-0 register prefetch (overlaps with phase A)
    int bn = t >> 1, bk = (t & 1) * 16;
    bf16x8 pb[2];
    #pragma unroll
    for (int j = 0; j < 2; ++j)
        pb[j] = *(const bf16x8*)&Wt[(size_t)bn * HD + bk + j * 8];

    {   // ---- phase A: wave per node, 8 nodes per wave, lane = 4 cols --------
        int c4 = lane * 4;
        float4 sc = *(const float4*)&scale[c4];
        float4 sh = *(const float4*)&shift[c4];
        for (int g = 0; g < 8; ++g) {
            int r = w * 8 + g;
            int n = m0 + r;
            float4 acc = make_float4(0.f, 0.f, 0.f, 0.f);
            if (n < NN) {
                float sn = selfn[n];
                bf16x4 hv = *(const bf16x4*)&h0[(size_t)n * HD + c4];
                acc.x = fmaxf((float)hv[0] * sc.x + sh.x, 0.f) * sn;
                acc.y = fmaxf((float)hv[1] * sc.y + sh.y, 0.f) * sn;
                acc.z = fmaxf((float)hv[2] * sc.z + sh.z, 0.f) * sn;
                acc.w = fmaxf((float)hv[3] * sc.w + sh.w, 0.f) * sn;
                unsigned e = row_start[n], e1 = row_start[n + 1];
                for (; e + 2 <= e1; e += 2) {
                    int s0 = ecol[e], s1 = ecol[e + 1];
                    float n0 = enorm[e], n1 = enorm[e + 1];
                    bf16x4 u0 = *(const bf16x4*)&h0[(size_t)s0 * HD + c4];
                    bf16x4 u1 = *(const bf16x4*)&h0[(size_t)s1 * HD + c4];
                    acc.x += fmaxf((float)u0[0] * sc.x + sh.x, 0.f) * n0
                           + fmaxf((float)u1[0] * sc.x + sh.x, 0.f) * n1;
                    acc.y += fmaxf((float)u0[1] * sc.y + sh.y, 0.f) * n0
                           + fmaxf((float)u1[1] * sc.y + sh.y, 0.f) * n1;
                    acc.z += fmaxf((float)u0[2] * sc.z + sh.z, 0.f) * n0
                           + fmaxf((float)u1[2] * sc.z + sh.z, 0.f) * n1;
                    acc.w += fmaxf((float)u0[3] * sc.w + sh.w, 0.f) * n0
                           + fmaxf((float)u1[3] * sc.w + sh.w, 0.f) * n1;
                }
                if (e < e1) {
                    int s0 = ecol[e];
                    float n0 = enorm[e];
                    bf16x4 u0 = *(const bf16x4*)&h0[(size_t)s0 * HD + c4];
                    acc.x += fmaxf((float)u0[0] * sc.x + sh.x, 0.f) * n0;
                    acc.y += fmaxf((float)u0[1] * sc.y + sh.y, 0.f) * n0;
                    acc.z += fmaxf((float)u0[2] * sc.z + sh.z, 0.f) * n0;
                    acc.w += fmaxf((float)u0[3] * sc.w + sh.w, 0.f) * n0;
                }
            }
            bf16x4 o;
            o[0] = (__bf16)acc.x; o[1] = (__bf16)acc.y;
            o[2] = (__bf16)acc.z; o[3] = (__bf16)acc.w;
            // swizzled store: granule (16B) = lane>>1, swz = gran ^ (r&7)
            int swz = ((lane >> 1) ^ (r & 7));
            *(bf16x4*)&sA[r * 256 + swz * 8 + (lane & 1) * 4] = o;
        }
    }

    // ---- phase B: K-256 GEMM, 8 chunks of 32 ---------------------------------
    floatx4 cacc[4][2] = {};
    for (int k0 = 0; k0 < 256; k0 += 32) {
        *(bf16x8*)&sB[bn * 36 + bk]     = pb[0];
        *(bf16x8*)&sB[bn * 36 + bk + 8] = pb[1];
        __syncthreads();

        if (k0 + 32 < 256) {
            #pragma unroll
            for (int j = 0; j < 2; ++j)
                pb[j] = *(const bf16x8*)&Wt[(size_t)bn * HD + k0 + 32 + bk + j * 8];
        }

        bf16x8 af[4], bfr[2];
        int gbase = (k0 >> 3) + quad;
        #pragma unroll
        for (int mi = 0; mi < 4; ++mi) {
            int row = mi * 16 + l16;
            af[mi] = *(const bf16x8*)&sA[row * 256 + ((gbase ^ (l16 & 7)) << 3)];
        }
        #pragma unroll
        for (int ni = 0; ni < 2; ++ni)
            bfr[ni] = *(const bf16x8*)&sB[(w * 32 + ni * 16 + l16) * 36 + quad * 8];
        #pragma unroll
        for (int mi = 0; mi < 4; ++mi)
            #pragma unroll
            for (int ni = 0; ni < 2; ++ni)
                cacc[mi][ni] = __builtin_amdgcn_mfma_f32_16x16x32_bf16(
                    af[mi], bfr[ni], cacc[mi][ni], 0, 0, 0);
        __syncthreads();
    }

    // ---- epilogue: bias, C-write, per-column BN partials ---------------------
    float bw[2];
    #pragma unroll
    for (int ni = 0; ni < 2; ++ni) bw[ni] = b1[w * 32 + ni * 16 + l16];
    float ls[2] = {0.f, 0.f}, lq[2] = {0.f, 0.f};
    #pragma unroll
    for (int mi = 0; mi < 4; ++mi) {
        #pragma unroll
        for (int r_ = 0; r_ < 4; ++r_) {
            int row = m0 + mi * 16 + quad * 4 + r_;
            if (row < NN) {
                #pragma unroll
                for (int ni = 0; ni < 2; ++ni) {
                    float v = cacc[mi][ni][r_] + bw[ni];
                    C[(size_t)row * HD + w * 32 + ni * 16 + l16] = (__bf16)v;
                    ls[ni] += v;
                    lq[ni] += v * v;
                }
            }
        }
    }
    #pragma unroll
    for (int ni = 0; ni < 2; ++ni) {
        ls[ni] += __shfl_xor(ls[ni], 16, 64);
        ls[ni] += __shfl_xor(ls[ni], 32, 64);
        lq[ni] += __shfl_xor(lq[ni], 16, 64);
        lq[ni] += __shfl_xor(lq[ni], 32, 64);
    }
    if (lane < 16) {
        #pragma unroll
        for (int ni = 0; ni < 2; ++ni) {
            int ci = w * 32 + ni * 16 + l16;
            part[(size_t)blockIdx.x * 512 + ci]       = ls[ni];
            part[(size_t)blockIdx.x * 512 + 256 + ci] = lq[ni];
        }
    }
}

// Stage 2: one block per column c; reduce nb per-block partials, emit scale/shift.
__global__ void __launch_bounds__(256) bn_scale(const float* __restrict__ part, int nb,
                                                const float* __restrict__ gamma,
                                                const float* __restrict__ beta,
                                                float* __restrict__ scale,
                                                float* __restrict__ shift) {
    __shared__ float rs[256], rq[256];
    int t = threadIdx.x;
    int c = blockIdx.x;
    float s = 0.f, q = 0.f;
    for (int j = t; j < nb; j += 256) {
        s += part[(size_t)j * 512 + c];
        q += part[(size_t)j * 512 + 256 + c];
    }
    rs[t] = s; rq[t] = q;
    __syncthreads();
    for (int off = 128; off > 0; off >>= 1) {
        if (t < off) { rs[t] += rs[t + off]; rq[t] += rq[t + off]; }
        __syncthreads();
    }
    if (t == 0) {
        const float inv_n = 1.0f / (float)NN;
        float mu  = rs[0] * inv_n;
        float var = rq[0] * inv_n - mu * mu;
        float rstd = rsqrtf(var + 1e-5f);
        float sc = gamma[c] * rstd;
        scale[c] = sc;
        shift[c] = beta[c] - mu * sc;
    }
}

// ---- layer-2 collapse: z[n] = relu_bn(h[n]) . w2lw  (one wave per node) -----
__global__ void __launch_bounds__(256) bn_dot(const __bf16* __restrict__ h,
                                              const float* __restrict__ scale,
                                              const float* __restrict__ shift,
                                              const float* __restrict__ w2lw,
                                              float* __restrict__ z) {
    int tid = blockIdx.x * 256 + threadIdx.x;
    int n = tid >> 6;
    if (n >= NN) return;
    int l = tid & 63;
    int c4 = l * 4;
    bf16x4 a = *(const bf16x4*)&h[(size_t)n * HD + c4];
    float4 sc = *(const float4*)&scale[c4];
    float4 sh = *(const float4*)&shift[c4];
    float4 wv = *(const float4*)&w2lw[c4];
    float d = fmaxf((float)a[0] * sc.x + sh.x, 0.f) * wv.x
            + fmaxf((float)a[1] * sc.y + sh.y, 0.f) * wv.y
            + fmaxf((float)a[2] * sc.z + sh.z, 0.f) * wv.z
            + fmaxf((float)a[3] * sc.w + sh.w, 0.f) * wv.w;
    #pragma unroll
    for (int off = 32; off > 0; off >>= 1) d += __shfl_down(d, off, 64);
    if (l == 0) z[n] = d;
}

// ---- fused final: per-graph wave; lanes stride nodes; scalar edge loop ------
__global__ void __launch_bounds__(256) pool_fused(const float* __restrict__ z,
                                                  const float* __restrict__ selfn,
                                                  const float* __restrict__ b2lw,
                                                  const unsigned* __restrict__ row_start,
                                                  const int* __restrict__ ecol,
                                                  const float* __restrict__ enorm,
                                                  const unsigned* __restrict__ gstart,
                                                  const float* __restrict__ lb,
                                                  float* __restrict__ out) {
    int tid = blockIdx.x * 256 + threadIdx.x;
    int g = tid >> 6;
    if (g >= NG) return;
    int l = tid & 63;
    unsigned s0 = gstart[g], s1 = gstart[g + 1];
    float bb = *b2lw;
    float s = 0.f;
    for (unsigned i = s0 + l; i < s1; i += 64) {
        float d = selfn[i] * z[i] + bb;
        unsigned e0 = row_start[i], e1 = row_start[i + 1];
        for (unsigned e = e0; e < e1; ++e)
            d += enorm[e] * z[ecol[e]];
        s += d;
    }
    #pragma unroll
    for (int off = 32; off > 0; off >>= 1) s += __shfl_down(s, off, 64);
    if (l == 0) out[g] = s / fmaxf((float)(s1 - s0), 1.0f) + lb[0];
}

// ---- driver -----------------------------------------------------------------
extern "C" void kernel_launch(void* const* d_in, const int* in_sizes, int n_in,
                              void* d_out, int out_size, void* d_ws, size_t ws_size,
                              hipStream_t stream) {
    const int*   x     = (const int*)d_in[0];
    const int*   ei    = (const int*)d_in[1];
    const int*   batch = (const int*)d_in[2];
    const float* emb   = (const float*)d_in[3];
    const float* Ws    = (const float*)d_in[4];
    const float* bs    = (const float*)d_in[5];
    const float* gam   = (const float*)d_in[6];
    const float* bet   = (const float*)d_in[7];
    const float* lw    = (const float*)d_in[8];
    const float* lb    = (const float*)d_in[9];
    float* out = (float*)d_out;

    const int* src = ei;
    const int* dst = ei + NE;

    // workspace carve-up (256-B aligned)
    char* p = (char*)d_ws;
    size_t off = 0;
    auto carve = [&](size_t bytes) { void* r = p + off; off = (off + bytes + 255) & ~(size_t)255; return r; };
    __bf16*   buf0   = (__bf16*)carve((size_t)NN * HD * 2);   // conv0 (bf16)
    __bf16*   buf1   = (__bf16*)carve((size_t)NN * HD * 2);   // conv1 (bf16)
    __bf16*   xb     = (__bf16*)carve((size_t)NN * 64 * 2);   // x as bf16, pad 64
    __bf16*   dW0t   = (__bf16*)carve(HD * 64 * 2);
    __bf16*   Wt     = (__bf16*)carve((size_t)HD * HD * 2);   // layer-1 only
    float*    w2lw   = (float*)carve(HD * 4);
    float*    b2lw   = (float*)carve(256);
    unsigned* deg    = (unsigned*)carve(NN * 4);
    float*    dinv   = (float*)carve(NN * 4);
    float*    selfn  = (float*)carve(NN * 4);
    unsigned* csum   = (unsigned*)carve(256 * 4);
    unsigned* row_s  = (unsigned*)carve((NN + 1) * 4);
    unsigned* cursor = (unsigned*)carve(NN * 4);
    int*      ecol   = (int*)carve(NE * 4);
    float*    enorm  = (float*)carve(NE * 4);
    float*    part   = (float*)carve((size_t)GNB * 512 * 4);  // 3.2 MB, [blk][512]
    float*    scale  = (float*)carve(HD * 4);
    float*    shift  = (float*)carve(HD * 4);
    unsigned* gstart = (unsigned*)carve((NG + 1) * 4);
    float*    zbuf   = (float*)carve(NN * 4);
    (void)ws_size; (void)n_in; (void)in_sizes; (void)out_size;

    // params + weight transposes + deg zeroing + x->bf16, all in one dispatch
    prep_params<<<NF + 2 + HD + ZB + CVB, HD, 0, stream>>>(
        emb, Ws, bs, lw, dW0t, w2lw, b2lw, Wt, deg, x, xb);

    // degrees, CSR build with inline norm + graph bounds in tail blocks
    deg_kernel<<<(NE + 255) / 256, 256, 0, stream>>>(dst, deg, NE);
    chunk_sum_dinv<<<NCH, SCAN_CH, 0, stream>>>(deg, csum, dinv, selfn);
    chunk_apply<<<NCH, SCAN_CH, 0, stream>>>(deg, csum, row_s, cursor);
    csr_fill_gb<<<EB + (NG + 256) / 256, 256, 0, stream>>>(
        src, dst, dinv, cursor, ecol, enorm, batch, gstart);

    // layer 0: aggregate-into-LDS + encoder GEMM + BN stats, one kernel
    enc_fused<<<ENB, 512, 0, stream>>>(
        xb, dW0t, bs, selfn, row_s, ecol, enorm, buf0, part);
    bn_scale<<<HD, 256, 0, stream>>>(part, ENB, gam, bet, scale, shift);

    // layer 1 fully fused: aggregate relu_bn(conv0) into LDS + GEMM + stats
    gcn_fused<<<GNB, 512, 0, stream>>>(
        buf0, scale, shift, Wt, bs + HD, selfn, row_s, ecol, enorm, buf1, part);
    bn_scale<<<HD, 256, 0, stream>>>(part, GNB, gam + HD, bet + HD, scale, shift);

    // layer 2 (collapsed): z = relu_bn(conv1)@(W2 lw); fused agg+pool
    bn_dot<<<(NN * 64 + 255) / 256, 256, 0, stream>>>(buf1, scale, shift, w2lw, zbuf);
    pool_fused<<<(NG * 64 + 255) / 256, 256, 0, stream>>>(
        zbuf, selfn, b2lw, row_s, ecol, enorm, gstart, lb, out);
}